// Round 9
// baseline (872.732 us; speedup 1.0000x reference)
//
#include <hip/hip_runtime.h>
#include <hip/hip_bf16.h>
#include <stdint.h>

// Problem constants
#define E_TOTAL 800000
#define NNODES  50000
#define NGRAPHS 64
#define NPRED   8
#define MPAD    50048          // node rows padded (well, to 64 here: 782*64)
#define EBLK    12500          // 800000/64 edge blocks
#define NBLK    782            // 50048/64 node blocks

// Weight tile: K=32, 320 out-cols. Pair-row layout: rows (2j,2j+1) share a
// 128B stripe of 8 16B chunks; chunk index = (c4 | ((r&1)<<2)) ^ ((r>>1)&7)
// (the proven 128B-stripe XOR family -> conflict-free b128 reads).
// 320/2 * 128 = 20480 B.
#define TILE_B  20480
#define SCR_B   40960          // block scratch: 64 rows x 320 cols bf16 (640B rows)
#define LDSZ    (2*TILE_B + SCR_B)   // 81920 B -> TWO blocks per CU

typedef short v8s __attribute__((ext_vector_type(8)));
typedef float v4f __attribute__((ext_vector_type(4)));
typedef float f4  __attribute__((ext_vector_type(4)));

__device__ __forceinline__ void gload_lds16(const void* g, void* l) {
    __builtin_amdgcn_global_load_lds(
        (const __attribute__((address_space(1))) uint32_t*)g,
        (__attribute__((address_space(3))) uint32_t*)l, 16, 0, 0);
}

__device__ __forceinline__ short f2bf_s(float f) {
    __hip_bfloat16 h = __float2bfloat16(f);
    return *reinterpret_cast<short*>(&h);
}

// ---------------------------------------------------------------------------
// Fused MLP chain, 256 threads = 4 waves, 64 rows/block, 2 blocks/CU (80KB
// LDS each). Wave wc owns ALL 64 rows x cols [wc*80, wc*80+80): acc = 4
// panels x 5 frags (80 VGPR). Per K=32 tile per wave: 5 B-frag + 4 A-frag
// ds_read_b128 for 20 MFMAs. 2-slot tile ping-pong, one barrier per tile:
//   [vmcnt(0); barrier; stage(t+1 -> slot^1); compute(t)]
// The per-tile drain is hidden by the SIBLING block on the same CU (the
// experiment: does block-level TLP lift the ~50% idle time?).
// ---------------------------------------------------------------------------
template <bool EDGE>
__global__ __launch_bounds__(256, 2)
void chain_kernel(const float* __restrict__ x, const int* __restrict__ ei,
                  const float* __restrict__ ea,
                  const __hip_bfloat16* __restrict__ aggrb,
                  const char* __restrict__ wimg,
                  const float* __restrict__ b1, const float* __restrict__ b2,
                  const float* __restrict__ b3, const float* __restrict__ b4,
                  float* __restrict__ outp)
{
    __shared__ __align__(16) char lds[LDSZ];
    const int tid  = threadIdx.x;
    const int lane = tid & 63;
    const int wc   = tid >> 6;    // 0..3 (80-col quarter; wave owns all 64 rows)
    const int l15  = lane & 15;
    const int kk   = lane >> 4;   // 0..3 (k-chunk of 8)
    char* scr = lds + 2*TILE_B;
    const int rowbase = blockIdx.x*64;

    constexpr int KT1 = EDGE ? 2 : 4;   // L1 K-tiles (K=64 / K=128)
    constexpr int T   = KT1 + 30;       // + 10+10+10

    auto stagef = [&](int t, int slot_){
        // 20 segments of 1KB; wave w stages segs {i*4+w}, i=0..4
        const char* s = wimg + (size_t)t*TILE_B + (size_t)tid*16;
        char* d = lds + slot_*TILE_B + wc*1024;
#pragma unroll
        for (int i = 0; i < 5; ++i) gload_lds16(s + i*4096, d + i*4096);
    };

    v4f acc[4][5];
#pragma unroll
    for (int p = 0; p < 4; ++p)
#pragma unroll
        for (int n = 0; n < 5; ++n) acc[p][n] = (v4f){0.f,0.f,0.f,0.f};

    // ---- bias preload ----
    float bb1[5], bb2[5], bb3[5], bb4[5];
#pragma unroll
    for (int n = 0; n < 5; ++n) {
        int colb = wc*80 + n*16 + l15;
        bb1[n] = b1[colb]; bb2[n] = b2[colb]; bb3[n] = b3[colb];
        if (EDGE) bb4[n] = (n < 2) ? b4[wc*32 + n*16 + l15] : 0.f;
        else      bb4[n] = b4[colb];
    }

    // ---- L1 A-fragments: af1[kt][panel] (each wave gathers all 64 rows) ----
    v8s af1[KT1][4];
    if (EDGE) {
#pragma unroll
        for (int p = 0; p < 4; ++p) {
            const int e = rowbase + p*16 + l15;
            // tile0 (k 0..31): kk 0,1 -> x[dst] feats 0..15; kk 2,3 -> x[src]
            const int nidx = (kk < 2) ? ei[E_TOTAL + e] : ei[e];
            const float* xs = x + (size_t)nidx*16 + (kk & 1)*8;
            f4 p0 = *(const f4*)xs, p1 = *(const f4*)(xs + 4);
            v8s a0, a1;
#pragma unroll
            for (int j = 0; j < 4; ++j) { a0[j] = f2bf_s(p0[j]); a0[4+j] = f2bf_s(p1[j]); }
            if (kk == 0) {        // tile1 (k 32..63): k 32..39 = edge_attr
                const float* es = ea + (size_t)e*8;
                f4 q0 = *(const f4*)es, q1 = *(const f4*)(es + 4);
#pragma unroll
                for (int j = 0; j < 4; ++j) { a1[j] = f2bf_s(q0[j]); a1[4+j] = f2bf_s(q1[j]); }
            } else {
#pragma unroll
                for (int j = 0; j < 8; ++j) a1[j] = 0;
            }
            af1[0][p] = a0; af1[1][p] = a1;
        }
    } else {
#pragma unroll
        for (int p = 0; p < 4; ++p) {
            const int grow = rowbase + p*16 + l15;
#pragma unroll
            for (int kt = 0; kt < KT1; ++kt)
                af1[kt][p] = *(const v8s*)((const char*)aggrb +
                    (size_t)grow*256 + kt*64 + kk*16);
        }
    }

    stagef(0, 0);
    int tt = 0, slot = 0;

#define TILE_BEGIN()                                                            \
    { asm volatile("s_waitcnt vmcnt(0)" ::: "memory");                          \
      __builtin_amdgcn_s_barrier();                                             \
      if (tt + 1 < T) stagef(tt + 1, slot ^ 1); }

#define TILE_END()  { ++tt; slot ^= 1; }

// B-frag: out-col r_, pair-row stripe layout; chunk (kk|((r&1)<<2)) ^ ((r>>1)&7)
#define MFMA_TILE(AF_, NT_, CB_)                                                \
    { const char* sl_ = lds + slot*TILE_B;                                      \
      _Pragma("unroll")                                                         \
      for (int n_ = 0; n_ < NT_; ++n_) {                                        \
        int r_ = (CB_) + n_*16 + l15;                                           \
        int ch_ = (kk | ((r_&1)<<2)) ^ ((r_>>1)&7);                             \
        v8s b_ = *(const v8s*)(sl_ + (r_>>1)*128 + (ch_<<4));                   \
        _Pragma("unroll")                                                       \
        for (int p_ = 0; p_ < 4; ++p_)                                          \
          acc[p_][n_] = __builtin_amdgcn_mfma_f32_16x16x32_bf16(                \
              (AF_)[p_], b_, acc[p_][n_], 0, 0, 0);                             \
      } }

// A-frag from scratch: row = p*16+l15 (640B rows, 40 chunks), chunk
// (kt*4+kk) ^ (row&7)  [XOR affects low 3 bits only -> bijective]
#define LOAD_AFRAG(KT_, A_)                                                     \
    { _Pragma("unroll")                                                         \
      for (int p_ = 0; p_ < 4; ++p_) {                                          \
        int c_ = ((KT_)*4 + kk) ^ (l15 & 7);                                    \
        (A_)[p_] = *(const v8s*)(scr + (p_*16 + l15)*640 + (c_<<4));            \
      } }

// Dump acc (C layout: col=wc*80+n*16+l15, row=p*16+kk*4+rr) -> scratch bf16,
// chunk XOR (row&7); reset acc; drain writes before the next barrier.
#define DUMP_RELU(BB_)                                                          \
    { __builtin_amdgcn_s_barrier();  /* readers of old scratch are done */      \
      _Pragma("unroll")                                                         \
      for (int p_ = 0; p_ < 4; ++p_)                                            \
        _Pragma("unroll")                                                       \
        for (int n_ = 0; n_ < 5; ++n_) {                                        \
          int col_ = wc*80 + n_*16 + l15;                                       \
          _Pragma("unroll")                                                     \
          for (int rr_ = 0; rr_ < 4; ++rr_) {                                   \
            int row_ = p_*16 + kk*4 + rr_;                                      \
            float v_ = fmaxf(acc[p_][n_][rr_] + (BB_)[n_], 0.f);                \
            *(__hip_bfloat16*)(scr + row_*640 +                                 \
                (((col_>>3) ^ (row_&7))<<4) + (col_&7)*2) = __float2bfloat16(v_); \
          }                                                                     \
          acc[p_][n_] = (v4f){0.f,0.f,0.f,0.f};                                 \
        }                                                                       \
      asm volatile("s_waitcnt lgkmcnt(0)" ::: "memory"); }

    // ---- L1 ----
#pragma unroll
    for (int kt = 0; kt < KT1; ++kt) { TILE_BEGIN(); MFMA_TILE(af1[kt], 5, wc*80); TILE_END(); }
    DUMP_RELU(bb1);
    // ---- L2 ----
#pragma unroll
    for (int kt = 0; kt < 10; ++kt) {
        TILE_BEGIN(); v8s A_[4]; LOAD_AFRAG(kt, A_); MFMA_TILE(A_, 5, wc*80); TILE_END();
    }
    DUMP_RELU(bb2);
    // ---- L3 ----
#pragma unroll
    for (int kt = 0; kt < 10; ++kt) {
        TILE_BEGIN(); v8s A_[4]; LOAD_AFRAG(kt, A_); MFMA_TILE(A_, 5, wc*80); TILE_END();
    }
    DUMP_RELU(bb3);
    // ---- L4 ----
    if (EDGE) {
#pragma unroll
        for (int kt = 0; kt < 10; ++kt) {
            TILE_BEGIN(); v8s A_[4]; LOAD_AFRAG(kt, A_); MFMA_TILE(A_, 2, wc*32); TILE_END();
        }
        // fused scatter-add: aggr[dst[e]*128 + col] += msg
#pragma unroll
        for (int p = 0; p < 4; ++p) {
#pragma unroll
            for (int rr = 0; rr < 4; ++rr) {
                int erow = rowbase + p*16 + kk*4 + rr;
                int d = ei[E_TOTAL + erow];
                float* ag = outp + (size_t)d*128;
#pragma unroll
                for (int n = 0; n < 2; ++n) {
                    int col = wc*32 + n*16 + l15;
                    atomicAdd(ag + col, acc[p][n][rr] + bb4[n]);
                }
            }
        }
    } else {
#pragma unroll
        for (int kt = 0; kt < 10; ++kt) {
            TILE_BEGIN(); v8s A_[4]; LOAD_AFRAG(kt, A_); MFMA_TILE(A_, 5, wc*80); TILE_END();
        }
        // store node fp32 [MPAD][320]
#pragma unroll
        for (int p = 0; p < 4; ++p) {
#pragma unroll
            for (int n = 0; n < 5; ++n) {
                int col = wc*80 + n*16 + l15;
#pragma unroll
                for (int rr = 0; rr < 4; ++rr) {
                    int grow = rowbase + p*16 + kk*4 + rr;
                    outp[(size_t)grow*320 + col] = acc[p][n][rr] + bb4[n];
                }
            }
        }
    }
#undef TILE_BEGIN
#undef TILE_END
#undef MFMA_TILE
#undef LOAD_AFRAG
#undef DUMP_RELU
}

// ---------------------------------------------------------------------------
// Repack fp32 W [K][N] -> pre-swizzled bf16 K=32 tile stream (KT tiles of
// 320 out-cols x 32 k, pair-row stripe layout matching the kernel reads).
// ---------------------------------------------------------------------------
__global__ void repack_tiles(const float* __restrict__ src, char* __restrict__ img,
                             int K, int N, int KT)
{
    int t = blockIdx.x*256 + threadIdx.x;
    if (t >= KT*10240) return;
    int tile = t / 10240;
    int rem  = t - tile*10240;
    int r    = rem >> 5;          // out col 0..319
    int k32  = rem & 31;
    int c4   = k32 >> 3;
    int j    = k32 & 7;
    int kg   = tile*32 + k32;
    float v = (r < N && kg < K) ? src[(size_t)kg*N + r] : 0.f;
    int ch = (c4 | ((r&1)<<2)) ^ ((r>>1)&7);
    size_t addr = (size_t)tile*TILE_B + (size_t)(r>>1)*128 + (ch<<4) + j*2;
    *(__hip_bfloat16*)(img + addr) = __float2bfloat16(v);
}

__global__ void pad_bias(const float* __restrict__ src, float* __restrict__ dst,
                         int N, int Npad)
{
    int t = blockIdx.x*256 + threadIdx.x;
    if (t < Npad) dst[t] = (t < N) ? src[t] : 0.f;
}

// aggr fp32 [MPAD][128] -> bf16 (rows >= NNODES forced to 0)
__global__ void cvt_aggr(const float* __restrict__ aggr, __hip_bfloat16* __restrict__ out)
{
    int t = blockIdx.x*256 + threadIdx.x;
    int row = t >> 7;
    float v = (row < NNODES) ? aggr[t] : 0.f;
    out[t] = __float2bfloat16(v);
}

__global__ void graph_starts_kernel(const int* __restrict__ batch,
                                    int* __restrict__ starts)
{
    int g = threadIdx.x;
    if (g > NGRAPHS) return;
    int lo = 0, hi = NNODES;
    while (lo < hi) {
        int mid = (lo + hi) >> 1;
        if (batch[mid] < g) lo = mid + 1; else hi = mid;
    }
    starts[g] = lo;
}

// Mean pool: node fp32 [MPAD][320] (valid cols 0..299) -> pooled [64][300]
__global__ void pool_kernel(const float* __restrict__ node,
                            const int* __restrict__ starts,
                            float* __restrict__ pooled)
{
    __shared__ float red[8][32];
    int g   = blockIdx.x;
    int col = blockIdx.y*32 + (threadIdx.x & 31);
    int rl  = threadIdx.x >> 5;
    int s = starts[g], e = starts[g + 1];
    float sum = 0.f;
    if (col < 300)
        for (int i = s + rl; i < e; i += 8) sum += node[(size_t)i*320 + col];
    red[rl][threadIdx.x & 31] = sum;
    __syncthreads();
    if (rl == 0 && col < 300) {
        float tot = 0.f;
#pragma unroll
        for (int r = 0; r < 8; ++r) tot += red[r][threadIdx.x & 31];
        float cnt = (float)(e - s);
        pooled[g*300 + col] = tot / fmaxf(cnt, 1.0f);
    }
}

__global__ void final_kernel(const float* __restrict__ pooled,
                             const float* __restrict__ lw,
                             const float* __restrict__ lb,
                             float* __restrict__ out)
{
    int t = threadIdx.x;          // 512 = 64 * 8
    int g = t / NPRED, p = t % NPRED;
    float s = lb[p];
    for (int k = 0; k < 300; ++k)
        s = fmaf(pooled[g*300 + k], lw[k*NPRED + p], s);
    out[g*NPRED + p] = s;
}

// ---------------------------------------------------------------------------
extern "C" void kernel_launch(void* const* d_in, const int* in_sizes, int n_in,
                              void* d_out, int out_size, void* d_ws, size_t ws_size,
                              hipStream_t stream)
{
    const float* x     = (const float*)d_in[0];
    const int*   ei    = (const int*)d_in[1];
    const float* ea    = (const float*)d_in[2];
    const int*   batch = (const int*)d_in[3];
    const float* mw[4] = {(const float*)d_in[4], (const float*)d_in[6],
                          (const float*)d_in[8], (const float*)d_in[10]};
    const float* mb[4] = {(const float*)d_in[5], (const float*)d_in[7],
                          (const float*)d_in[9], (const float*)d_in[11]};
    const float* nw[4] = {(const float*)d_in[12], (const float*)d_in[14],
                          (const float*)d_in[16], (const float*)d_in[18]};
    const float* nb[4] = {(const float*)d_in[13], (const float*)d_in[15],
                          (const float*)d_in[17], (const float*)d_in[19]};
    const float* lw = (const float*)d_in[20];
    const float* lb = (const float*)d_in[21];
    float* out = (float*)d_out;

    char* ws = (char*)d_ws;
    size_t off = 0;
    auto alloc = [&](size_t bytes) -> void* {
        void* p = ws + off;
        off += (bytes + 255) & ~(size_t)255;
        return p;
    };

    float*          aggr   = (float*)alloc((size_t)MPAD*128*4);          // 25.6 MB
    __hip_bfloat16* aggrb  = (__hip_bfloat16*)alloc((size_t)MPAD*128*2); // 12.8 MB
    float*          node   = (float*)alloc((size_t)MPAD*320*4);          // 64.1 MB
    char*           wimg_e = (char*)alloc((size_t)32*TILE_B);            // 640 KB
    char*           wimg_n = (char*)alloc((size_t)34*TILE_B);            // 680 KB
    float* mbp[4]; float* nbp[4];
    for (int i = 0; i < 4; ++i) { mbp[i] = (float*)alloc(320*4); nbp[i] = (float*)alloc(320*4); }
    float* pooled = (float*)alloc(64*300*4);
    int*   starts = (int*)alloc(65*4);

    // ---- weight repack into pre-swizzled K=32 tile streams ----
    const int mK[4]  = {40, 300, 300, 300},  mN[4]  = {300, 300, 300, 128};
    const int nK[4]  = {128, 300, 300, 300}, nN[4]  = {300, 300, 300, 300};
    const int mKT[4] = {2, 10, 10, 10},      nKT[4] = {4, 10, 10, 10};
    {
        size_t te = 0, tn = 0;
        for (int i = 0; i < 4; ++i) {
            repack_tiles<<<mKT[i]*40, 256, 0, stream>>>(mw[i], wimg_e + te*TILE_B,
                                                        mK[i], mN[i], mKT[i]);
            te += mKT[i];
            repack_tiles<<<nKT[i]*40, 256, 0, stream>>>(nw[i], wimg_n + tn*TILE_B,
                                                        nK[i], nN[i], nKT[i]);
            tn += nKT[i];
            pad_bias<<<2, 256, 0, stream>>>(mb[i], mbp[i], mN[i], 320);
            pad_bias<<<2, 256, 0, stream>>>(nb[i], nbp[i], nN[i], 320);
        }
    }
    hipMemsetAsync(aggr, 0, (size_t)NNODES*128*4, stream);
    graph_starts_kernel<<<1, 128, 0, stream>>>(batch, starts);

    // ---- edge phase: message MLP + fused scatter, all 800K edges ----
    chain_kernel<true><<<EBLK, 256, 0, stream>>>(
        x, ei, ea, nullptr, wimg_e, mbp[0], mbp[1], mbp[2], mbp[3], aggr);

    // ---- node phase ----
    cvt_aggr<<<(MPAD*128)/256, 256, 0, stream>>>(aggr, aggrb);
    chain_kernel<false><<<NBLK, 256, 0, stream>>>(
        x, ei, ea, aggrb, wimg_n, nbp[0], nbp[1], nbp[2], nbp[3], node);

    pool_kernel<<<dim3(64, 10), 256, 0, stream>>>(node, starts, pooled);
    final_kernel<<<1, 512, 0, stream>>>(pooled, lw, lb, out);
}